// Round 1
// baseline (249429.053 us; speedup 1.0000x reference)
//
#include <hip/hip_runtime.h>
#include <math.h>

#define SEQ   8192
#define NIN   256
#define H     2048
#define NBLK  256
#define NTHR  256

typedef unsigned long long u64;

// ---- ws layout (bytes from d_ws) ----
// 0 : u64 rec[2][8][NBLK]   (32 KB)
//     rec[slot][j][b] = { hi32 = step tag, lo32 = float bits of h[8b+j] }
//
// Fused tag+value transport: each h element travels as ONE 8-byte relaxed
// agent-scope atomic (single-copy atomic => self-validating, no fence, no
// separate tag array). Consumer thread tid polls exactly block tid's 8
// records: the poll IS the data fetch (one coherence-point hop per step
// instead of two), finished lanes drop out of the poll (pressure decays),
// and poll reads are spread over 128 cache lines instead of 8.

__global__ void lstm_init(const float* __restrict__ h0, float* __restrict__ ws)
{
    const int b = threadIdx.x;   // one block of 256
    u64* rec = (u64*)ws;
    #pragma unroll
    for (int j = 0; j < 8; ++j) {
        unsigned hv = __builtin_bit_cast(unsigned, h0[8 * b + j]);
        rec[j * NBLK + b]        = (u64)hv;                    // slot0: tag 0 + h0
        rec[2048 + j * NBLK + b] = ((u64)0xFFFFFFFFu) << 32;   // slot1: invalid tag
    }
}

// Persistent LSTM. fp32 weights register-resident, fp64 recurrence math,
// fused {tag,h} u64 transport. Block b owns h[8b..8b+8); wave wv computes
// gate wv. Lane ln holds w_hh[R][32ln..32ln+32) for its 8 rows.
__global__ void __launch_bounds__(NTHR, 1)
lstm_persist(const float* __restrict__ x, const float* __restrict__ c0,
             const float* __restrict__ w_ih, const float* __restrict__ w_hh,
             const float* __restrict__ b_ih, const float* __restrict__ b_hh,
             const float* __restrict__ w_lin, const float* __restrict__ b_lin,
             float* __restrict__ out, float* __restrict__ ws)
{
    const int b = blockIdx.x, tid = threadIdx.x;
    const int wv = tid >> 6, ln = tid & 63;
    u64* rec = (u64*)ws;

    __shared__ float  h_lds[H + H / 32];   // stride-33 padding: 2-way bank = free
    __shared__ double gsum[4][8];
    __shared__ double bias_s[4][8];
    __shared__ double red0[4], red1[4];

    if (tid < 32) {
        int g = tid >> 3, r = tid & 7;
        int R = g * H + b * 8 + r;
        bias_s[g][r] = (double)b_ih[R] + (double)b_hh[R];
    }
    // cell state lives in wave-0 registers (lane j<8 owns c[8b+j])
    double c_reg = (wv == 0 && ln < 8) ? (double)c0[b * 8 + ln] : 0.0;

    float wreg[8][32];
    float wih[8][4];
    #pragma unroll
    for (int r = 0; r < 8; ++r) {
        const int R = wv * H + b * 8 + r;
        const float4* wp = (const float4*)(w_hh + (size_t)R * H + ln * 32);
        #pragma unroll
        for (int q = 0; q < 8; ++q) ((float4*)wreg[r])[q] = wp[q];
        *(float4*)wih[r] = *(const float4*)(w_ih + (size_t)R * NIN + ln * 4);
    }
    __syncthreads();

    float4 xr = *(const float4*)(x + ln * 4);
    float4 xn = xr;

    for (int t = 0; t < SEQ; ++t) {
        const int slot = t & 1;
        const u64* rs = rec + slot * 2048;

        // per-thread poll of its producer's 8 fused records (coalesced 512B
        // wave-loads: rec index j*NBLK+tid, lanes contiguous)
        {
            u64 v[8];
            for (;;) {
                bool ok = true;
                #pragma unroll
                for (int j = 0; j < 8; ++j) {
                    v[j] = __hip_atomic_load(rs + j * NBLK + tid,
                                             __ATOMIC_RELAXED, __HIP_MEMORY_SCOPE_AGENT);
                    ok &= ((unsigned)(v[j] >> 32) == (unsigned)t);
                }
                if (ok) break;   // per-lane exit: done lanes stop issuing loads
                __builtin_amdgcn_s_sleep(2);
            }
            const int base = 8 * tid + (tid >> 2);
            #pragma unroll
            for (int j = 0; j < 8; ++j)
                h_lds[base + j] = __builtin_bit_cast(float, (unsigned)v[j]);
        }
        __syncthreads();   // A: step-t h fully staged in LDS

        if (t + 1 < SEQ) xn = *(const float4*)(x + (size_t)(t + 1) * NIN + ln * 4);

        // matvec: fp32 w x fp32 h, fp64 accumulate
        float hbuf[32];
        {
            const float* hp = &h_lds[33 * ln];
            #pragma unroll
            for (int q = 0; q < 32; ++q) hbuf[q] = hp[q];
        }
        double acc[8];
        #pragma unroll
        for (int r = 0; r < 8; ++r)
            acc[r] = (double)wih[r][0] * (double)xr.x + (double)wih[r][1] * (double)xr.y
                   + (double)wih[r][2] * (double)xr.z + (double)wih[r][3] * (double)xr.w;
        #pragma unroll
        for (int q = 0; q < 32; ++q) {
            const double hq = (double)hbuf[q];
            #pragma unroll
            for (int r = 0; r < 8; ++r)
                acc[r] = fma((double)wreg[r][q], hq, acc[r]);
        }
        #pragma unroll
        for (int off = 32; off >= 1; off >>= 1) {
            #pragma unroll
            for (int r = 0; r < 8; ++r) acc[r] += __shfl_xor(acc[r], off, 64);
        }
        if (ln == 0) {
            #pragma unroll
            for (int r = 0; r < 8; ++r) gsum[wv][r] = acc[r];
        }
        __syncthreads();   // B: gsum ready; h_lds reads done (safe to restage)

        // wave 0: activations (lanes 0-31, one each), update, publish
        if (wv == 0) {
            double actv = 0.0;
            if (ln < 32) {
                const int g = ln >> 3, j = ln & 7;
                double vs = gsum[g][j] + bias_s[g][j];
                actv = (g == 2) ? tanh(vs) : 1.0 / (1.0 + exp(-vs));
            }
            const int j = ln & 7;
            double ai = __shfl(actv, j,      64);
            double af = __shfl(actv, j + 8,  64);
            double ag = __shfl(actv, j + 16, 64);
            double ao = __shfl(actv, j + 24, 64);
            if (ln < 8) {
                double c = af * c_reg + ai * ag;
                c_reg = c;
                float hnew = (float)(ao * tanh(c));
                u64 pv = ((u64)(unsigned)(t + 1) << 32)
                       | (u64)__builtin_bit_cast(unsigned, hnew);
                u64* dst = rec + (1 - slot) * 2048 + ln * NBLK + b;
                // single 8B atomic: tag+value together, no fence needed
                __hip_atomic_store(dst, pv, __ATOMIC_RELAXED, __HIP_MEMORY_SCOPE_AGENT);
            }
        }
        xr = xn;
    }

    // ---- epilogue: block 0 computes logits from h(SEQ) (slot 0, tag SEQ) ----
    if (b == 0) {
        u64 v[8];
        for (;;) {
            bool ok = true;
            #pragma unroll
            for (int j = 0; j < 8; ++j) {
                v[j] = __hip_atomic_load(rec + j * NBLK + tid,
                                         __ATOMIC_RELAXED, __HIP_MEMORY_SCOPE_AGENT);
                ok &= ((unsigned)(v[j] >> 32) == (unsigned)SEQ);
            }
            if (ok) break;
            __builtin_amdgcn_s_sleep(2);
        }
        double a0 = 0., a1 = 0.;
        #pragma unroll
        for (int j = 0; j < 8; ++j) {
            const float hv = __builtin_bit_cast(float, (unsigned)v[j]);
            const int k = 8 * tid + j;
            a0 = fma((double)w_lin[k],     (double)hv, a0);
            a1 = fma((double)w_lin[H + k], (double)hv, a1);
        }
        #pragma unroll
        for (int off = 32; off >= 1; off >>= 1) {
            a0 += __shfl_xor(a0, off, 64);
            a1 += __shfl_xor(a1, off, 64);
        }
        if (ln == 0) { red0[wv] = a0; red1[wv] = a1; }
        __syncthreads();
        if (tid == 0) {
            out[0] = (float)(red0[0] + red0[1] + red0[2] + red0[3] + (double)b_lin[0]);
            out[1] = (float)(red1[0] + red1[1] + red1[2] + red1[3] + (double)b_lin[1]);
        }
    }
}

extern "C" void kernel_launch(void* const* d_in, const int* in_sizes, int n_in,
                              void* d_out, int out_size, void* d_ws, size_t ws_size,
                              hipStream_t stream) {
    const float* x     = (const float*)d_in[0];
    const float* h0    = (const float*)d_in[1];
    const float* c0    = (const float*)d_in[2];
    const float* w_ih  = (const float*)d_in[3];
    const float* w_hh  = (const float*)d_in[4];
    const float* b_ih  = (const float*)d_in[5];
    const float* b_hh  = (const float*)d_in[6];
    const float* w_lin = (const float*)d_in[7];
    const float* b_lin = (const float*)d_in[8];
    float* out = (float*)d_out;
    float* ws  = (float*)d_ws;

    lstm_init<<<1, NTHR, 0, stream>>>(h0, ws);
    lstm_persist<<<NBLK, NTHR, 0, stream>>>(
        x, c0, w_ih, w_hh, b_ih, b_hh, w_lin, b_lin, out, ws);
}

// Round 3
// 216469.482 us; speedup vs baseline: 1.1523x; 1.1523x over previous
//
#include <hip/hip_runtime.h>
#include <math.h>

#define SEQ   8192
#define NIN   256
#define H     2048
#define NBLK  256
#define NTHR  256
#define NREP  16

typedef unsigned long long u64;

// ---- ws layout (bytes from d_ws) ----
// 0     : float    hA[2][H]              (16 KB) h transport, ping-pong
// 16384 : unsigned tags[2][NREP][NBLK]   (32 KB) REPLICATED step tags
//
// Contention model: agent-scope (sc1) accesses serialize per cache line at
// the coherence point. Fixes vs round-0:
//  - tags replicated x16: consumer b polls replica (b&15) -> 16 same-line
//    pollers instead of 256. Producer publishes the tag to all 16 replicas
//    with 16 parallel lane-stores (lanes 0..15).
//  - h broadcast goes through XCD L2: producers publish h with sc1 stores
//    (data at coherence point before tag), consumers do ONE agent acquire
//    fence per step (buffer_inv) then NORMAL cached loads -> 32 blocks/XCD
//    share one L2 fill per line (MALL requests per line 256 -> ~8).

__global__ void lstm_init(const float* __restrict__ h0, float* __restrict__ ws)
{
    const int b = threadIdx.x;   // one block of 256
    unsigned* tags = (unsigned*)(ws + 2 * H);
    #pragma unroll
    for (int r = 0; r < 8; ++r) {
        unsigned hv = __builtin_bit_cast(unsigned, h0[8 * b + r]);
        __hip_atomic_store((unsigned*)ws + 8 * b + r, hv,
                           __ATOMIC_RELAXED, __HIP_MEMORY_SCOPE_AGENT);
    }
    #pragma unroll
    for (int r = 0; r < NREP; ++r) {
        __hip_atomic_store(&tags[r * NBLK + b], 0u,
                           __ATOMIC_RELAXED, __HIP_MEMORY_SCOPE_AGENT);
        __hip_atomic_store(&tags[(NREP + r) * NBLK + b], 0xFFFFFFFFu,
                           __ATOMIC_RELAXED, __HIP_MEMORY_SCOPE_AGENT);
    }
}

// Wave-0-only poll of replica `rep`: lane ln checks packed tag pairs
// (2 u64 = 4 tags) until all 256 tags == t. Relaxed sc1 loads, no fences.
__device__ __forceinline__ void wave_poll_tags(const u64* tp, unsigned t, int ln)
{
    const u64 want = ((u64)t << 32) | (u64)t;
    for (;;) {
        u64 a = __hip_atomic_load(tp + ln,      __ATOMIC_RELAXED, __HIP_MEMORY_SCOPE_AGENT);
        u64 b = __hip_atomic_load(tp + 64 + ln, __ATOMIC_RELAXED, __HIP_MEMORY_SCOPE_AGENT);
        if (__all((a == want) && (b == want))) break;
        __builtin_amdgcn_s_sleep(2);
    }
}

// Persistent LSTM. fp32 weights register-resident, fp64 recurrence math,
// fp32 h transport. Block b owns h[8b..8b+8); wave wv computes gate wv.
// Lane ln holds w_hh[R][32ln..32ln+32) for its 8 rows.
__global__ void __launch_bounds__(NTHR, 1)
lstm_persist(const float* __restrict__ x, const float* __restrict__ c0,
             const float* __restrict__ w_ih, const float* __restrict__ w_hh,
             const float* __restrict__ b_ih, const float* __restrict__ b_hh,
             const float* __restrict__ w_lin, const float* __restrict__ b_lin,
             float* __restrict__ out, float* __restrict__ ws)
{
    const int b = blockIdx.x, tid = threadIdx.x;
    const int wv = tid >> 6, ln = tid & 63;
    float*    hA   = ws;
    unsigned* tags = (unsigned*)(ws + 2 * H);     // [2][NREP][NBLK]
    const int rep  = b & (NREP - 1);

    __shared__ float  h_lds[H + H / 32];   // stride-33 padding
    __shared__ double gsum[4][8];
    __shared__ double bias_s[4][8];
    __shared__ double red0[4], red1[4];

    if (tid < 32) {
        int g = tid >> 3, r = tid & 7;
        int R = g * H + b * 8 + r;
        bias_s[g][r] = (double)b_ih[R] + (double)b_hh[R];
    }
    // cell state lives in wave-0 registers (lane j<8 owns c[8b+j])
    double c_reg = (wv == 0 && ln < 8) ? (double)c0[b * 8 + ln] : 0.0;

    float wreg[8][32];
    float wih[8][4];
    #pragma unroll
    for (int r = 0; r < 8; ++r) {
        const int R = wv * H + b * 8 + r;
        const float4* wp = (const float4*)(w_hh + (size_t)R * H + ln * 32);
        #pragma unroll
        for (int q = 0; q < 8; ++q) ((float4*)wreg[r])[q] = wp[q];
        *(float4*)wih[r] = *(const float4*)(w_ih + (size_t)R * NIN + ln * 4);
    }
    __syncthreads();

    float4 xr = *(const float4*)(x + ln * 4);
    float4 xn = xr;

    for (int t = 0; t < SEQ; ++t) {
        const int slot = t & 1;

        // issue x prefetch BEFORE poll/fence: value lands in regs, immune to
        // the L2 invalidate, and its latency hides under the poll.
        if (t + 1 < SEQ) xn = *(const float4*)(x + (size_t)(t + 1) * NIN + ln * 4);

        if (wv == 0)
            wave_poll_tags((const u64*)(tags + (slot * NREP + rep) * NBLK),
                           (unsigned)t, ln);
        __syncthreads();   // #1: step-t records are at the coherence point

        // ONE acquire fence per step: invalidate stale L1/L2 lines, then
        // fetch h with normal cached loads (shared L2 fill per XCD).
        __builtin_amdgcn_fence(__ATOMIC_ACQUIRE, "agent");
        {
            const float4* hp = (const float4*)(hA + slot * H) + tid * 2;
            float4 v0 = hp[0], v1 = hp[1];
            const int base = 8 * tid + (tid >> 2);
            h_lds[base + 0] = v0.x; h_lds[base + 1] = v0.y;
            h_lds[base + 2] = v0.z; h_lds[base + 3] = v0.w;
            h_lds[base + 4] = v1.x; h_lds[base + 5] = v1.y;
            h_lds[base + 6] = v1.z; h_lds[base + 7] = v1.w;
        }
        __syncthreads();   // #2: h staged in LDS

        // matvec: fp32 w x fp32 h, fp64 accumulate
        float hbuf[32];
        {
            const float* hp = &h_lds[33 * ln];
            #pragma unroll
            for (int q = 0; q < 32; ++q) hbuf[q] = hp[q];
        }
        double acc[8];
        #pragma unroll
        for (int r = 0; r < 8; ++r)
            acc[r] = (double)wih[r][0] * (double)xr.x + (double)wih[r][1] * (double)xr.y
                   + (double)wih[r][2] * (double)xr.z + (double)wih[r][3] * (double)xr.w;
        #pragma unroll
        for (int q = 0; q < 32; ++q) {
            const double hq = (double)hbuf[q];
            #pragma unroll
            for (int r = 0; r < 8; ++r)
                acc[r] = fma((double)wreg[r][q], hq, acc[r]);
        }
        #pragma unroll
        for (int off = 32; off >= 1; off >>= 1) {
            #pragma unroll
            for (int r = 0; r < 8; ++r) acc[r] += __shfl_xor(acc[r], off, 64);
        }
        if (ln == 0) {
            #pragma unroll
            for (int r = 0; r < 8; ++r) gsum[wv][r] = acc[r];
        }
        __syncthreads();   // #3

        // wave 0: activations (lanes 0-31, one each), update, publish
        if (wv == 0) {
            double actv = 0.0;
            if (ln < 32) {
                const int g = ln >> 3, j = ln & 7;
                double v = gsum[g][j] + bias_s[g][j];
                actv = (g == 2) ? tanh(v) : 1.0 / (1.0 + exp(-v));
            }
            const int j = ln & 7;
            double ai = __shfl(actv, j,      64);
            double af = __shfl(actv, j + 8,  64);
            double ag = __shfl(actv, j + 16, 64);
            double ao = __shfl(actv, j + 24, 64);
            if (ln < 8) {
                double c = af * c_reg + ai * ag;
                c_reg = c;
                float hnew = (float)(ao * tanh(c));
                unsigned* dst = (unsigned*)(hA + (1 - slot) * H) + 8 * b + ln;
                __hip_atomic_store(dst, __builtin_bit_cast(unsigned, hnew),
                                   __ATOMIC_RELAXED, __HIP_MEMORY_SCOPE_AGENT);
            }
            // order data stores before tag stores (atomic->atomic: waitcnt suffices)
            asm volatile("s_waitcnt vmcnt(0)" ::: "memory");
            if (ln < NREP)
                __hip_atomic_store(&tags[((1 - slot) * NREP + ln) * NBLK + b],
                                   (unsigned)(t + 1),
                                   __ATOMIC_RELAXED, __HIP_MEMORY_SCOPE_AGENT);
        }
        xr = xn;
    }

    // ---- epilogue: block 0 computes logits from h(SEQ) (slot 0, tag SEQ) ----
    if (b == 0) {
        if (wv == 0) wave_poll_tags((const u64*)tags, (unsigned)SEQ, ln);
        __syncthreads();
        __builtin_amdgcn_fence(__ATOMIC_ACQUIRE, "agent");
        double a0 = 0., a1 = 0.;
        {
            const float4* hp = (const float4*)hA + tid * 2;
            float4 v0 = hp[0], v1 = hp[1];
            const float hv[8] = { v0.x, v0.y, v0.z, v0.w, v1.x, v1.y, v1.z, v1.w };
            #pragma unroll
            for (int q = 0; q < 8; ++q) {
                const int k = 8 * tid + q;
                a0 = fma((double)w_lin[k],     (double)hv[q], a0);
                a1 = fma((double)w_lin[H + k], (double)hv[q], a1);
            }
        }
        #pragma unroll
        for (int off = 32; off >= 1; off >>= 1) {
            a0 += __shfl_xor(a0, off, 64);
            a1 += __shfl_xor(a1, off, 64);
        }
        if (ln == 0) { red0[wv] = a0; red1[wv] = a1; }
        __syncthreads();
        if (tid == 0) {
            out[0] = (float)(red0[0] + red0[1] + red0[2] + red0[3] + (double)b_lin[0]);
            out[1] = (float)(red1[0] + red1[1] + red1[2] + red1[3] + (double)b_lin[1]);
        }
    }
}

extern "C" void kernel_launch(void* const* d_in, const int* in_sizes, int n_in,
                              void* d_out, int out_size, void* d_ws, size_t ws_size,
                              hipStream_t stream) {
    const float* x     = (const float*)d_in[0];
    const float* h0    = (const float*)d_in[1];
    const float* c0    = (const float*)d_in[2];
    const float* w_ih  = (const float*)d_in[3];
    const float* w_hh  = (const float*)d_in[4];
    const float* b_ih  = (const float*)d_in[5];
    const float* b_hh  = (const float*)d_in[6];
    const float* w_lin = (const float*)d_in[7];
    const float* b_lin = (const float*)d_in[8];
    float* out = (float*)d_out;
    float* ws  = (float*)d_ws;

    lstm_init<<<1, NTHR, 0, stream>>>(h0, ws);
    lstm_persist<<<NBLK, NTHR, 0, stream>>>(
        x, c0, w_ih, w_hh, b_ih, b_hh, w_lin, b_lin, out, ws);
}

// Round 4
// 196541.492 us; speedup vs baseline: 1.2691x; 1.1014x over previous
//
#include <hip/hip_runtime.h>
#include <math.h>

#define SEQ    8192
#define NIN    256
#define H      2048
#define NBLK   256
#define NTHR   256
#define NREP   16   // tag replicas
#define NHREP  4    // h-vector replicas

typedef unsigned long long u64;

// ---- ws layout (bytes from d_ws) ----
// 0     : float    hA[2][NHREP][H]        (64 KB) h transport, ping-pong, x4 replicas
// 65536 : unsigned tags[2][NREP][NBLK]    (32 KB) step tags, x16 replicas
//
// All transport is relaxed agent-scope (sc1) — round-3 showed per-block
// acquire fences destroy each other's L2 fills (invalidate storm).
// This round reduces PER-LINE queue depth at the coherence point, holding
// request count constant:
//   - consumer polls tag replica (b&15): 16 pollers/line instead of 256
//   - consumer reads h replica (b&3):    64 readers/line instead of 256
// Producer publish: lanes 0-31 store 8 h values x 4 replicas (1 store/lane),
// vmcnt(0), lanes 0-15 store the tag to 16 replicas (1 store/lane).

__global__ void lstm_init(const float* __restrict__ h0, float* __restrict__ ws)
{
    const int b = threadIdx.x;   // one block of 256
    unsigned* tags = (unsigned*)(ws + 2 * NHREP * H);
    #pragma unroll
    for (int r = 0; r < 8; ++r) {
        unsigned hv = __builtin_bit_cast(unsigned, h0[8 * b + r]);
        #pragma unroll
        for (int rep = 0; rep < NHREP; ++rep)
            __hip_atomic_store((unsigned*)ws + rep * H + 8 * b + r, hv,
                               __ATOMIC_RELAXED, __HIP_MEMORY_SCOPE_AGENT);
    }
    #pragma unroll
    for (int rep = 0; rep < NREP; ++rep) {
        __hip_atomic_store(&tags[rep * NBLK + b], 0u,
                           __ATOMIC_RELAXED, __HIP_MEMORY_SCOPE_AGENT);
        __hip_atomic_store(&tags[(NREP + rep) * NBLK + b], 0xFFFFFFFFu,
                           __ATOMIC_RELAXED, __HIP_MEMORY_SCOPE_AGENT);
    }
}

// Wave-0-only poll of one tag replica: lane ln checks packed tag pairs
// (2 u64 = 4 tags) until all 256 tags == t. Relaxed sc1 loads, no fences.
__device__ __forceinline__ void wave_poll_tags(const u64* tp, unsigned t, int ln)
{
    const u64 want = ((u64)t << 32) | (u64)t;
    for (;;) {
        u64 a = __hip_atomic_load(tp + ln,      __ATOMIC_RELAXED, __HIP_MEMORY_SCOPE_AGENT);
        u64 b = __hip_atomic_load(tp + 64 + ln, __ATOMIC_RELAXED, __HIP_MEMORY_SCOPE_AGENT);
        if (__all((a == want) && (b == want))) break;
        __builtin_amdgcn_s_sleep(2);
    }
}

// Persistent LSTM. fp32 weights register-resident, fp64 recurrence math,
// fp32 h transport. Block b owns h[8b..8b+8); wave wv computes gate wv.
// Lane ln holds w_hh[R][32ln..32ln+32) for its 8 rows.
__global__ void __launch_bounds__(NTHR, 1)
lstm_persist(const float* __restrict__ x, const float* __restrict__ c0,
             const float* __restrict__ w_ih, const float* __restrict__ w_hh,
             const float* __restrict__ b_ih, const float* __restrict__ b_hh,
             const float* __restrict__ w_lin, const float* __restrict__ b_lin,
             float* __restrict__ out, float* __restrict__ ws)
{
    const int b = blockIdx.x, tid = threadIdx.x;
    const int wv = tid >> 6, ln = tid & 63;
    float*    hA   = ws;                            // [2][NHREP][H]
    unsigned* tags = (unsigned*)(ws + 2 * NHREP * H); // [2][NREP][NBLK]
    const u64* tagsU = (const u64*)tags;
    const int rep  = b & (NREP - 1);
    const int hrep = b & (NHREP - 1);

    __shared__ float  h_lds[H + H / 32];   // stride-33 padding
    __shared__ double gsum[4][8];
    __shared__ double bias_s[4][8];
    __shared__ double red0[4], red1[4];

    if (tid < 32) {
        int g = tid >> 3, r = tid & 7;
        int R = g * H + b * 8 + r;
        bias_s[g][r] = (double)b_ih[R] + (double)b_hh[R];
    }
    // cell state lives in wave-0 registers (lane j<8 owns c[8b+j])
    double c_reg = (wv == 0 && ln < 8) ? (double)c0[b * 8 + ln] : 0.0;

    float wreg[8][32];
    float wih[8][4];
    #pragma unroll
    for (int r = 0; r < 8; ++r) {
        const int R = wv * H + b * 8 + r;
        const float4* wp = (const float4*)(w_hh + (size_t)R * H + ln * 32);
        #pragma unroll
        for (int q = 0; q < 8; ++q) ((float4*)wreg[r])[q] = wp[q];
        *(float4*)wih[r] = *(const float4*)(w_ih + (size_t)R * NIN + ln * 4);
    }
    __syncthreads();

    float4 xr = *(const float4*)(x + ln * 4);
    float4 xn = xr;

    for (int t = 0; t < SEQ; ++t) {
        const int slot = t & 1;

        // issue x prefetch BEFORE the poll: HBM latency hides under the wait,
        // value lands in registers.
        if (t + 1 < SEQ) xn = *(const float4*)(x + (size_t)(t + 1) * NIN + ln * 4);

        if (wv == 0)
            wave_poll_tags(tagsU + (slot * NREP + rep) * (NBLK / 2), (unsigned)t, ln);
        __syncthreads();   // #1: all 256 records of step t are at coherence point

        // fetch h from replica (b&3): thread tid owns floats [8*tid, 8*tid+8)
        {
            const u64* hp = (const u64*)(hA + (slot * NHREP + hrep) * H) + tid * 4;
            const int base = 8 * tid + (tid >> 2);
            #pragma unroll
            for (int q = 0; q < 4; ++q) {
                u64 v = __hip_atomic_load(hp + q, __ATOMIC_RELAXED, __HIP_MEMORY_SCOPE_AGENT);
                union { u64 u; float2 f; } cv; cv.u = v;
                h_lds[base + 2 * q]     = cv.f.x;
                h_lds[base + 2 * q + 1] = cv.f.y;
            }
        }
        __syncthreads();   // #2

        // matvec: fp32 w x fp32 h, fp64 accumulate
        float hbuf[32];
        {
            const float* hp = &h_lds[33 * ln];
            #pragma unroll
            for (int q = 0; q < 32; ++q) hbuf[q] = hp[q];
        }
        double acc[8];
        #pragma unroll
        for (int r = 0; r < 8; ++r)
            acc[r] = (double)wih[r][0] * (double)xr.x + (double)wih[r][1] * (double)xr.y
                   + (double)wih[r][2] * (double)xr.z + (double)wih[r][3] * (double)xr.w;
        #pragma unroll
        for (int q = 0; q < 32; ++q) {
            const double hq = (double)hbuf[q];
            #pragma unroll
            for (int r = 0; r < 8; ++r)
                acc[r] = fma((double)wreg[r][q], hq, acc[r]);
        }
        #pragma unroll
        for (int off = 32; off >= 1; off >>= 1) {
            #pragma unroll
            for (int r = 0; r < 8; ++r) acc[r] += __shfl_xor(acc[r], off, 64);
        }
        if (ln == 0) {
            #pragma unroll
            for (int r = 0; r < 8; ++r) gsum[wv][r] = acc[r];
        }
        __syncthreads();   // #3

        // wave 0: activations (lanes 0-31, one each), update, publish
        if (wv == 0) {
            double actv = 0.0;
            if (ln < 32) {
                const int g = ln >> 3, j = ln & 7;
                double v = gsum[g][j] + bias_s[g][j];
                actv = (g == 2) ? tanh(v) : 1.0 / (1.0 + exp(-v));
            }
            const int j = ln & 7;
            double ai = __shfl(actv, j,      64);
            double af = __shfl(actv, j + 8,  64);
            double ag = __shfl(actv, j + 16, 64);
            double ao = __shfl(actv, j + 24, 64);
            float hnewf = 0.0f;
            if (ln < 8) {
                double c = af * c_reg + ai * ag;
                c_reg = c;
                hnewf = (float)(ao * tanh(c));
            }
            // lanes 0-31: publish value (ln&7) to replica (ln>>3)
            float hb = __shfl(hnewf, ln & 7, 64);
            if (ln < 8 * NHREP) {
                unsigned* dst = (unsigned*)(hA + ((1 - slot) * NHREP + (ln >> 3)) * H)
                              + 8 * b + (ln & 7);
                __hip_atomic_store(dst, __builtin_bit_cast(unsigned, hb),
                                   __ATOMIC_RELAXED, __HIP_MEMORY_SCOPE_AGENT);
            }
            // order data stores before tag stores (atomic->atomic: waitcnt suffices)
            asm volatile("s_waitcnt vmcnt(0)" ::: "memory");
            if (ln < NREP)
                __hip_atomic_store(&tags[((1 - slot) * NREP + ln) * NBLK + b],
                                   (unsigned)(t + 1),
                                   __ATOMIC_RELAXED, __HIP_MEMORY_SCOPE_AGENT);
        }
        xr = xn;
    }

    // ---- epilogue: block 0 computes logits from h(SEQ) (slot 0, tag SEQ) ----
    if (b == 0) {
        if (wv == 0) wave_poll_tags(tagsU, (unsigned)SEQ, ln);   // slot 0, replica 0
        __syncthreads();
        double a0 = 0., a1 = 0.;
        {
            const u64* hp = (const u64*)hA + tid * 4;   // slot 0, replica 0
            #pragma unroll
            for (int q = 0; q < 4; ++q) {
                u64 v = __hip_atomic_load(hp + q, __ATOMIC_RELAXED, __HIP_MEMORY_SCOPE_AGENT);
                union { u64 u; float2 f; } cv; cv.u = v;
                const int k = 8 * tid + 2 * q;
                a0 = fma((double)w_lin[k],         (double)cv.f.x, a0);
                a0 = fma((double)w_lin[k + 1],     (double)cv.f.y, a0);
                a1 = fma((double)w_lin[H + k],     (double)cv.f.x, a1);
                a1 = fma((double)w_lin[H + k + 1], (double)cv.f.y, a1);
            }
        }
        #pragma unroll
        for (int off = 32; off >= 1; off >>= 1) {
            a0 += __shfl_xor(a0, off, 64);
            a1 += __shfl_xor(a1, off, 64);
        }
        if (ln == 0) { red0[wv] = a0; red1[wv] = a1; }
        __syncthreads();
        if (tid == 0) {
            out[0] = (float)(red0[0] + red0[1] + red0[2] + red0[3] + (double)b_lin[0]);
            out[1] = (float)(red1[0] + red1[1] + red1[2] + red1[3] + (double)b_lin[1]);
        }
    }
}

extern "C" void kernel_launch(void* const* d_in, const int* in_sizes, int n_in,
                              void* d_out, int out_size, void* d_ws, size_t ws_size,
                              hipStream_t stream) {
    const float* x     = (const float*)d_in[0];
    const float* h0    = (const float*)d_in[1];
    const float* c0    = (const float*)d_in[2];
    const float* w_ih  = (const float*)d_in[3];
    const float* w_hh  = (const float*)d_in[4];
    const float* b_ih  = (const float*)d_in[5];
    const float* b_hh  = (const float*)d_in[6];
    const float* w_lin = (const float*)d_in[7];
    const float* b_lin = (const float*)d_in[8];
    float* out = (float*)d_out;
    float* ws  = (float*)d_ws;

    lstm_init<<<1, NTHR, 0, stream>>>(h0, ws);
    lstm_persist<<<NBLK, NTHR, 0, stream>>>(
        x, c0, w_ih, w_hh, b_ih, b_hh, w_lin, b_lin, out, ws);
}

// Round 8
// 180319.470 us; speedup vs baseline: 1.3833x; 1.0900x over previous
//
#include <hip/hip_runtime.h>
#include <math.h>

#define SEQ   8192
#define NIN   256
#define H     2048
#define NBLK  256
#define NTHR  256

typedef unsigned long long u64;

// ---- ws layout (bytes from d_ws), K chosen at launch from ws_size ----
// 0        : float hS[K][H]        sweeping h transport (slot = t % K)
// K*H*4    : unsigned tags[2][NBLK] ping-pong step tags (sc1, as round-0)
//
// Model: step time = aggregate line-requests at the coherence point
// (~2 req/ns measured). Baseline: 46K req/step, 32K of them the h
// broadcast (256 blocks x 128 lines, all sc1/uncached). Sweeping slots
// let consumers use NORMAL CACHED loads after the tag gate: first touch
// fills the XCD L2 once, 32 blocks share it -> h requests ~32K -> ~1-2K.
// Slot-reuse staleness (distance K) is fixed by per-block acquire fences
// every P=K/2 steps, staggered by block id (NOT per-step -> no R3 storm).

__global__ void lstm_init(const float* __restrict__ h0, float* __restrict__ hS,
                          unsigned* __restrict__ tags)
{
    const int j = threadIdx.x;   // one block of 256
    #pragma unroll
    for (int r = 0; r < 8; ++r) hS[8 * j + r] = h0[8 * j + r];   // slot 0 = h(0)
    tags[j]        = 0u;           // slot-parity 0 carries tag 0
    tags[NBLK + j] = 0xFFFFFFFFu;  // parity 1 not ready
}

// Wave-0-only poll: lane ln checks packed tag pairs (2 u64 = 4 tags) until
// all 256 tags == t. Relaxed sc1 loads (uncached, exact) — round-0 proven.
__device__ __forceinline__ void wave_poll_tags(const u64* tp, unsigned t, int ln)
{
    const u64 want = ((u64)t << 32) | (u64)t;
    for (;;) {
        u64 a = __hip_atomic_load(tp + ln,      __ATOMIC_RELAXED, __HIP_MEMORY_SCOPE_AGENT);
        u64 b = __hip_atomic_load(tp + 64 + ln, __ATOMIC_RELAXED, __HIP_MEMORY_SCOPE_AGENT);
        if (__all((a == want) && (b == want))) break;
        __builtin_amdgcn_s_sleep(2);
    }
}

// Persistent LSTM. fp32 weights register-resident, fp64 recurrence math.
// Block b owns h[8b..8b+8); wave wv computes gate wv. Lane ln holds
// w_hh[R][32ln..32ln+32) for its 8 rows.
__global__ void __launch_bounds__(NTHR, 1)
lstm_persist(const float* __restrict__ x, const float* __restrict__ c0,
             const float* __restrict__ w_ih, const float* __restrict__ w_hh,
             const float* __restrict__ b_ih, const float* __restrict__ b_hh,
             const float* __restrict__ w_lin, const float* __restrict__ b_lin,
             float* __restrict__ out, float* __restrict__ hS,
             unsigned* __restrict__ tags, int K, int P)
{
    const int b = blockIdx.x, tid = threadIdx.x;
    const int wv = tid >> 6, ln = tid & 63;
    const u64* tagsU = (const u64*)tags;

    __shared__ float  h_lds[H + H / 32];   // stride-33 padding
    __shared__ double gsum[4][8];
    __shared__ double bias_s[4][8];
    __shared__ double red0[4], red1[4];

    if (tid < 32) {
        int g = tid >> 3, r = tid & 7;
        int R = g * H + b * 8 + r;
        bias_s[g][r] = (double)b_ih[R] + (double)b_hh[R];
    }
    // cell state lives in wave-0 registers (lane j<8 owns c[8b+j])
    double c_reg = (wv == 0 && ln < 8) ? (double)c0[b * 8 + ln] : 0.0;

    float wreg[8][32];
    float wih[8][4];
    #pragma unroll
    for (int r = 0; r < 8; ++r) {
        const int R = wv * H + b * 8 + r;
        const float4* wp = (const float4*)(w_hh + (size_t)R * H + ln * 32);
        #pragma unroll
        for (int q = 0; q < 8; ++q) ((float4*)wreg[r])[q] = wp[q];
        *(float4*)wih[r] = *(const float4*)(w_ih + (size_t)R * NIN + ln * 4);
    }
    __syncthreads();

    float4 xr = *(const float4*)(x + ln * 4);
    float4 xn = xr;

    int scur = 0;                    // slot of step t's h
    int fcnt = (b % P) + 1;          // staggered fence countdown

    for (int t = 0; t < SEQ; ++t) {
        const int tagslot = t & 1;
        const int snext = (scur + 1 == K) ? 0 : scur + 1;

        // x prefetch before the poll: latency hides under the wait
        if (t + 1 < SEQ) xn = *(const float4*)(x + (size_t)(t + 1) * NIN + ln * 4);

        if (wv == 0)
            wave_poll_tags(tagsU + tagslot * (NBLK / 2), (unsigned)t, ln);
        __syncthreads();   // #1: all 256 h(t) records are at the coherence point

        // fetch h with NORMAL CACHED loads (slot untouched this generation:
        // first-touch miss -> MALL -> L2 fill shared by the whole XCD)
        {
            const float4* hp = (const float4*)(hS + (size_t)scur * H) + tid * 2;
            float4 v0 = hp[0], v1 = hp[1];
            const int base = 8 * tid + (tid >> 2);
            h_lds[base + 0] = v0.x; h_lds[base + 1] = v0.y;
            h_lds[base + 2] = v0.z; h_lds[base + 3] = v0.w;
            h_lds[base + 4] = v1.x; h_lds[base + 5] = v1.y;
            h_lds[base + 6] = v1.z; h_lds[base + 7] = v1.w;
        }
        __syncthreads();   // #2: h staged in LDS

        // periodic staggered fence: invalidate this CU's L1 + XCD L2 so
        // slot reuse (distance K) never reads stale lines. Amortized: P=K/2.
        if (--fcnt == 0) {
            fcnt = P;
            if (tid == 0) __builtin_amdgcn_fence(__ATOMIC_ACQUIRE, "agent");
        }

        // matvec: fp32 w x fp32 h, fp64 accumulate
        float hbuf[32];
        {
            const float* hp = &h_lds[33 * ln];
            #pragma unroll
            for (int q = 0; q < 32; ++q) hbuf[q] = hp[q];
        }
        double acc[8];
        #pragma unroll
        for (int r = 0; r < 8; ++r)
            acc[r] = (double)wih[r][0] * (double)xr.x + (double)wih[r][1] * (double)xr.y
                   + (double)wih[r][2] * (double)xr.z + (double)wih[r][3] * (double)xr.w;
        #pragma unroll
        for (int q = 0; q < 32; ++q) {
            const double hq = (double)hbuf[q];
            #pragma unroll
            for (int r = 0; r < 8; ++r)
                acc[r] = fma((double)wreg[r][q], hq, acc[r]);
        }
        #pragma unroll
        for (int off = 32; off >= 1; off >>= 1) {
            #pragma unroll
            for (int r = 0; r < 8; ++r) acc[r] += __shfl_xor(acc[r], off, 64);
        }
        if (ln == 0) {
            #pragma unroll
            for (int r = 0; r < 8; ++r) gsum[wv][r] = acc[r];
        }
        __syncthreads();   // #3

        // wave 0: activations (lanes 0-31, one each), update, publish
        if (wv == 0) {
            double actv = 0.0;
            if (ln < 32) {
                const int g = ln >> 3, j = ln & 7;
                double v = gsum[g][j] + bias_s[g][j];
                actv = (g == 2) ? tanh(v) : 1.0 / (1.0 + exp(-v));
            }
            const int j = ln & 7;
            double ai = __shfl(actv, j,      64);
            double af = __shfl(actv, j + 8,  64);
            double ag = __shfl(actv, j + 16, 64);
            double ao = __shfl(actv, j + 24, 64);
            if (ln < 8) {
                double c = af * c_reg + ai * ag;
                c_reg = c;
                float hnew = (float)(ao * tanh(c));
                // sc1 publish straight to the coherence point (bypasses caches)
                unsigned* dst = (unsigned*)(hS + (size_t)snext * H) + 8 * b + ln;
                __hip_atomic_store(dst, __builtin_bit_cast(unsigned, hnew),
                                   __ATOMIC_RELAXED, __HIP_MEMORY_SCOPE_AGENT);
            }
            // order data stores before tag store (atomic->atomic: waitcnt suffices)
            asm volatile("s_waitcnt vmcnt(0)" ::: "memory");
            if (ln == 0)
                __hip_atomic_store(&tags[(1 - tagslot) * NBLK + b], (unsigned)(t + 1),
                                   __ATOMIC_RELAXED, __HIP_MEMORY_SCOPE_AGENT);
        }
        xr = xn;
        scur = snext;
    }

    // ---- epilogue: block 0 computes logits from h(SEQ) (slot scur) ----
    if (b == 0) {
        if (wv == 0) wave_poll_tags(tagsU, (unsigned)SEQ, ln);  // parity 0
        __syncthreads();
        if (tid == 0) __builtin_amdgcn_fence(__ATOMIC_ACQUIRE, "agent");
        __syncthreads();
        double a0 = 0., a1 = 0.;
        {
            const float4* hp = (const float4*)(hS + (size_t)scur * H) + tid * 2;
            float4 v0 = hp[0], v1 = hp[1];
            const float hv[8] = { v0.x, v0.y, v0.z, v0.w, v1.x, v1.y, v1.z, v1.w };
            #pragma unroll
            for (int q = 0; q < 8; ++q) {
                const int k = 8 * tid + q;
                a0 = fma((double)w_lin[k],     (double)hv[q], a0);
                a1 = fma((double)w_lin[H + k], (double)hv[q], a1);
            }
        }
        #pragma unroll
        for (int off = 32; off >= 1; off >>= 1) {
            a0 += __shfl_xor(a0, off, 64);
            a1 += __shfl_xor(a1, off, 64);
        }
        if (ln == 0) { red0[wv] = a0; red1[wv] = a1; }
        __syncthreads();
        if (tid == 0) {
            out[0] = (float)(red0[0] + red0[1] + red0[2] + red0[3] + (double)b_lin[0]);
            out[1] = (float)(red1[0] + red1[1] + red1[2] + red1[3] + (double)b_lin[1]);
        }
    }
}

extern "C" void kernel_launch(void* const* d_in, const int* in_sizes, int n_in,
                              void* d_out, int out_size, void* d_ws, size_t ws_size,
                              hipStream_t stream) {
    const float* x     = (const float*)d_in[0];
    const float* h0    = (const float*)d_in[1];
    const float* c0    = (const float*)d_in[2];
    const float* w_ih  = (const float*)d_in[3];
    const float* w_hh  = (const float*)d_in[4];
    const float* b_ih  = (const float*)d_in[5];
    const float* b_hh  = (const float*)d_in[6];
    const float* w_lin = (const float*)d_in[7];
    const float* b_lin = (const float*)d_in[8];
    float* out = (float*)d_out;
    float* ws  = (float*)d_ws;

    // size the sweep ring from the workspace: K slots of H floats + tags
    const size_t slotB = (size_t)H * 4, tagB = 2 * NBLK * 4;
    int K = 2;
    while (K < 1024 && ((size_t)(K * 2) * slotB + tagB) <= ws_size) K *= 2;
    int P = K / 2; if (P < 1) P = 1;

    float*    hS   = ws;
    unsigned* tags = (unsigned*)(ws + (size_t)K * H);

    lstm_init<<<1, NTHR, 0, stream>>>(h0, hS, tags);
    lstm_persist<<<NBLK, NTHR, 0, stream>>>(
        x, c0, w_ih, w_hh, b_ih, b_hh, w_lin, b_lin, out, hS, tags, K, P);
}